// Round 1
// baseline (4970.852 us; speedup 1.0000x reference)
//
#include <hip/hip_runtime.h>
#include <math.h>

#define NN 3000
#define HF 256

// ---------------- kernels ----------------

__global__ void scatter_edges(float* __restrict__ A, const int* __restrict__ ei, int E, int n) {
    int e = blockIdx.x * 256 + threadIdx.x;
    if (e < E) {
        int r = ei[e];
        int c = ei[E + e];
        atomicAdd(&A[(size_t)r * n + c], 1.0f);
    }
}

__global__ void rowsum_dis(const float* __restrict__ A, int n, float* __restrict__ dis) {
    int row = blockIdx.x;
    __shared__ float sd[256];
    float s = 0.f;
    for (int c = threadIdx.x; c < n; c += 256) s += A[(size_t)row * n + c];
    sd[threadIdx.x] = s;
    __syncthreads();
    for (int st = 128; st > 0; st >>= 1) {
        if (threadIdx.x < st) sd[threadIdx.x] += sd[threadIdx.x + st];
        __syncthreads();
    }
    if (threadIdx.x == 0) dis[row] = 1.0f / sqrtf(sd[0] + 2.0f);
}

// C[i,o] = rs[i] * sum_k X[i,k] * W[o,k]    (X: n x K, W: m x K row-major)
__global__ void gemm_nt_scale(const float* __restrict__ X, const float* __restrict__ Wm,
                              float* __restrict__ C, int n, int K, int m,
                              const float* __restrict__ rs) {
    __shared__ float As[64][17];
    __shared__ float Bs[64][17];
    int tx = threadIdx.x & 15, ty = threadIdx.x >> 4;
    int rowBase = blockIdx.y * 64, colBase = blockIdx.x * 64;
    float acc[4][4] = {};
    for (int k0 = 0; k0 < K; k0 += 16) {
        for (int i = 0; i < 4; i++) {
            int l = threadIdx.x + i * 256;
            int r = l >> 4, c = l & 15;
            int gr = rowBase + r, gc = k0 + c;
            As[r][c] = (gr < n && gc < K) ? X[(size_t)gr * K + gc] : 0.f;
            int br = colBase + r;
            Bs[r][c] = (br < m && gc < K) ? Wm[(size_t)br * K + gc] : 0.f;
        }
        __syncthreads();
        for (int kk = 0; kk < 16; kk++) {
            float a[4], b[4];
            for (int i = 0; i < 4; i++) a[i] = As[ty * 4 + i][kk];
            for (int j = 0; j < 4; j++) b[j] = Bs[tx * 4 + j][kk];
            for (int i = 0; i < 4; i++)
                for (int j = 0; j < 4; j++) acc[i][j] += a[i] * b[j];
        }
        __syncthreads();
    }
    for (int i = 0; i < 4; i++) {
        int gr = rowBase + ty * 4 + i;
        if (gr >= n) continue;
        float rsv = rs ? rs[gr] : 1.0f;
        for (int j = 0; j < 4; j++) {
            int gc = colBase + tx * 4 + j;
            if (gc >= m) continue;
            C[(size_t)gr * m + gc] = rsv * acc[i][j];
        }
    }
}

// MODE 0: augment epilogue (zero diagonal).  C = A @ B, A: n x K, B: K x m
// MODE 1: gcn epilogue: C[i,o] = dis[i]*(acc + 2*z[i,o]) + bias[o], optional relu
template <int MODE>
__global__ void gemm_nn(const float* __restrict__ A, const float* __restrict__ B,
                        float* __restrict__ C, int n, int K, int m,
                        const float* __restrict__ dis, const float* __restrict__ z,
                        const float* __restrict__ bias, int relu) {
    __shared__ float As[64][17];
    __shared__ float Bs[16][65];
    int tx = threadIdx.x & 15, ty = threadIdx.x >> 4;
    int rowBase = blockIdx.y * 64, colBase = blockIdx.x * 64;
    float acc[4][4] = {};
    for (int k0 = 0; k0 < K; k0 += 16) {
        for (int i = 0; i < 4; i++) {
            int l = threadIdx.x + i * 256;
            int r = l >> 4, c = l & 15;
            int gr = rowBase + r, gc = k0 + c;
            As[r][c] = (gr < n && gc < K) ? A[(size_t)gr * K + gc] : 0.f;
            int br = l >> 6, bc = l & 63;
            int gbr = k0 + br, gbc = colBase + bc;
            Bs[br][bc] = (gbr < K && gbc < m) ? B[(size_t)gbr * m + gbc] : 0.f;
        }
        __syncthreads();
        for (int kk = 0; kk < 16; kk++) {
            float a[4], b[4];
            for (int i = 0; i < 4; i++) a[i] = As[ty * 4 + i][kk];
            for (int j = 0; j < 4; j++) b[j] = Bs[kk][tx * 4 + j];
            for (int i = 0; i < 4; i++)
                for (int j = 0; j < 4; j++) acc[i][j] += a[i] * b[j];
        }
        __syncthreads();
    }
    for (int i = 0; i < 4; i++) {
        int gr = rowBase + ty * 4 + i;
        if (gr >= n) continue;
        for (int j = 0; j < 4; j++) {
            int gc = colBase + tx * 4 + j;
            if (gc >= m) continue;
            float v = acc[i][j];
            if (MODE == 0) {
                if (gr == gc) v = 0.f;
            } else {
                v = dis[gr] * (v + 2.0f * z[(size_t)gr * m + gc]) + bias[gc];
                if (relu) v = fmaxf(v, 0.f);
            }
            C[(size_t)gr * m + gc] = v;
        }
    }
}

__global__ void make_A1(const float* __restrict__ A, float* __restrict__ T, int n) {
    int idx = blockIdx.x * 256 + threadIdx.x;
    if (idx < n * n) {
        int r = idx / n, c = idx - r * n;
        T[idx] = (r == c) ? 1.0f : A[idx];
    }
}

__global__ void wnorm(const float* __restrict__ w, float* __restrict__ out) {
    __shared__ float sd[256];
    float v = w[threadIdx.x];
    sd[threadIdx.x] = v * v;
    __syncthreads();
    for (int st = 128; st > 0; st >>= 1) {
        if (threadIdx.x < st) sd[threadIdx.x] += sd[threadIdx.x + st];
        __syncthreads();
    }
    if (threadIdx.x == 0) out[0] = sqrtf(sd[0]);
}

__global__ void score_k(const float* __restrict__ x, const float* __restrict__ w,
                        const float* __restrict__ nrm, float* __restrict__ s) {
    int row = blockIdx.x;
    __shared__ float sd[256];
    sd[threadIdx.x] = x[(size_t)row * HF + threadIdx.x] * w[threadIdx.x];
    __syncthreads();
    for (int st = 128; st > 0; st >>= 1) {
        if (threadIdx.x < st) sd[threadIdx.x] += sd[threadIdx.x + st];
        __syncthreads();
    }
    if (threadIdx.x == 0) s[row] = tanhf(sd[0] / nrm[0]);
}

// single-block bitonic sort of up to 4096 keys; key = (~mapped_score << 32) | idx
__global__ __launch_bounds__(1024) void topk_sort(const float* __restrict__ s, int n,
                                                  int* __restrict__ perm, int k) {
    __shared__ unsigned long long sk[4096];
    for (int i = threadIdx.x; i < 4096; i += 1024) {
        unsigned long long key;
        if (i < n) {
            unsigned u = __float_as_uint(s[i]);
            u = (u & 0x80000000u) ? ~u : (u | 0x80000000u);  // ascending map
            unsigned inv = ~u;                                // descending
            key = ((unsigned long long)inv << 32) | (unsigned)i;
        } else {
            key = 0xFFFFFFFFFFFFFFFFull;
        }
        sk[i] = key;
    }
    __syncthreads();
    for (int kk = 2; kk <= 4096; kk <<= 1) {
        for (int j = kk >> 1; j > 0; j >>= 1) {
            for (int i = threadIdx.x; i < 4096; i += 1024) {
                int ij = i ^ j;
                if (ij > i) {
                    bool up = ((i & kk) == 0);
                    unsigned long long a = sk[i], b = sk[ij];
                    if ((a > b) == up) { sk[i] = b; sk[ij] = a; }
                }
            }
            __syncthreads();
        }
    }
    for (int i = threadIdx.x; i < k; i += 1024) perm[i] = (int)(sk[i] & 0xFFFFFFFFu);
}

__global__ void gather_pool(const float* __restrict__ x, const int* __restrict__ perm,
                            const float* __restrict__ s, float* __restrict__ out) {
    int r = blockIdx.x, h = threadIdx.x;
    int p = perm[r];
    out[(size_t)r * HF + h] = x[(size_t)p * HF + h] * s[p];
}

__global__ void gather_adj(const float* __restrict__ Aaug, const int* __restrict__ perm,
                           float* __restrict__ out, int n, int k) {
    int idx = blockIdx.x * 256 + threadIdx.x;
    if (idx < k * k) {
        int r = idx / k, c = idx - r * k;
        out[idx] = Aaug[(size_t)perm[r] * n + perm[c]];
    }
}

__global__ void scatter_add(float* __restrict__ out, const float* __restrict__ xs,
                            const int* __restrict__ perm) {
    int r = blockIdx.x, h = threadIdx.x;
    out[(size_t)perm[r] * HF + h] += xs[(size_t)r * HF + h];
}

// ---------------- host ----------------

extern "C" void kernel_launch(void* const* d_in, const int* in_sizes, int n_in,
                              void* d_out, int out_size, void* d_ws, size_t ws_size,
                              hipStream_t stream) {
    const int* edge_index = (const int*)d_in[0];
    const float* x_param = (const float*)d_in[1];
    const float* W_down = (const float*)d_in[2];
    const float* b_down = (const float*)d_in[3];
    const float* pool_w = (const float*)d_in[4];
    const float* W_up = (const float*)d_in[5];
    const float* b_up = (const float*)d_in[6];
    const float* W_out = (const float*)d_in[7];
    const float* b_out = (const float*)d_in[8];
    float* out = (float*)d_out;

    const int E = in_sizes[0] / 2;  // 96000
    const int KS[3] = {2000, 1000, 500};

    // workspace layout (floats)
    float* w = (float*)d_ws;
    size_t off = 0;
    auto alloc = [&](size_t cnt) { float* p = w + off; off += cnt; return p; };
    float* As0 = alloc(9000000);
    float* As1 = alloc(4000000);
    float* As2 = alloc(1000000);
    float* A3  = alloc(250000);
    float* T1  = alloc(9000000);
    float* T2  = alloc(9000000);
    float* xs0 = alloc(768000);
    float* xs1 = alloc(512000);
    float* xs2 = alloc(256000);
    float* xp  = alloc(768000);
    float* xq  = alloc(768000);
    float* zt  = alloc(768000);
    float* sc  = alloc(3008);
    float* dis = alloc(3008);
    float* nrm = alloc(8);
    int* perm0 = (int*)alloc(2000);
    int* perm1 = (int*)alloc(1024);
    int* perm2 = (int*)alloc(512);

    auto gcn = [&](const float* A, const float* x, const float* Wm, const float* b,
                   int n, int fout, float* outp, int relu) {
        rowsum_dis<<<n, 256, 0, stream>>>(A, n, dis);
        dim3 gnt((fout + 63) / 64, (n + 63) / 64);
        gemm_nt_scale<<<gnt, 256, 0, stream>>>(x, Wm, zt, n, HF, fout, dis);
        dim3 gnn((fout + 63) / 64, (n + 63) / 64);
        gemm_nn<1><<<gnn, 256, 0, stream>>>(A, zt, outp, n, n, fout, dis, zt, b, relu);
    };

    // build A0
    hipMemsetAsync(As0, 0, (size_t)NN * NN * sizeof(float), stream);
    scatter_edges<<<(E + 255) / 256, 256, 0, stream>>>(As0, edge_index, E, NN);

    // x0 = relu(gcn(A0, x_param, Wd0, bd0))
    gcn(As0, x_param, W_down, b_down, NN, HF, xs0, 1);

    const float* Alevels[3] = {As0, As1, As2};
    float* Anext[3] = {As1, As2, A3};
    int* perms[3] = {perm0, perm1, perm2};
    const float* xlev[3] = {xs0, xs1, xs2};
    float* xnext[3] = {xs1, xs2, xq};
    int ns[4] = {NN, 2000, 1000, 500};

    for (int i = 0; i < 3; i++) {
        int n = ns[i], k = KS[i];
        // augment: T2 = (A + I)^2 with zero diag
        make_A1<<<(n * n + 255) / 256, 256, 0, stream>>>(Alevels[i], T1, n);
        dim3 gaug((n + 63) / 64, (n + 63) / 64);
        gemm_nn<0><<<gaug, 256, 0, stream>>>(T1, T1, T2, n, n, n, nullptr, nullptr, nullptr, 0);
        // scores
        wnorm<<<1, 256, 0, stream>>>(pool_w + (size_t)i * HF, nrm);
        score_k<<<n, 256, 0, stream>>>(xlev[i], pool_w + (size_t)i * HF, nrm, sc);
        topk_sort<<<1, 1024, 0, stream>>>(sc, n, perms[i], k);
        // pool
        gather_pool<<<k, 256, 0, stream>>>(xlev[i], perms[i], sc, xp);
        gather_adj<<<(k * k + 255) / 256, 256, 0, stream>>>(T2, perms[i], Anext[i], n, k);
        // down gcn
        gcn(Anext[i], xp, W_down + (size_t)(i + 1) * HF * HF, b_down + (size_t)(i + 1) * HF,
            k, HF, xnext[i], 1);
    }

    // up path: x currently in xq (500 x 256)
    // i=0 (j=2): n=1000
    {
        hipMemcpyAsync(xp, xs2, (size_t)1000 * HF * sizeof(float),
                       hipMemcpyDeviceToDevice, stream);
        scatter_add<<<500, 256, 0, stream>>>(xp, xq, perm2);
        gcn(As2, xp, W_up, b_up, 1000, HF, xq, 1);
    }
    // i=1 (j=1): n=2000
    {
        hipMemcpyAsync(xp, xs1, (size_t)2000 * HF * sizeof(float),
                       hipMemcpyDeviceToDevice, stream);
        scatter_add<<<1000, 256, 0, stream>>>(xp, xq, perm1);
        gcn(As1, xp, W_up + (size_t)HF * HF, b_up + HF, 2000, HF, xq, 1);
    }
    // i=2 (j=0): n=3000, final output, no relu, fout=40
    {
        hipMemcpyAsync(xp, xs0, (size_t)NN * HF * sizeof(float),
                       hipMemcpyDeviceToDevice, stream);
        scatter_add<<<2000, 256, 0, stream>>>(xp, xq, perm0);
        gcn(As0, xp, W_out, b_out, NN, 40, out, 0);
    }
}

// Round 2
// 2863.451 us; speedup vs baseline: 1.7360x; 1.7360x over previous
//
#include <hip/hip_runtime.h>
#include <math.h>

#define NN 3000
#define HF 256

typedef __attribute__((ext_vector_type(4))) float f32x4;
typedef __attribute__((ext_vector_type(4))) unsigned int u32x4;

__device__ inline void mfma_bf16(f32x4& d, u32x4 a, u32x4 b) {
    asm("v_mfma_f32_16x16x32_bf16 %0, %1, %2, %0" : "+v"(d) : "v"(a), "v"(b));
}

__device__ inline void gload16(const void* g, void* l) {
    __builtin_amdgcn_global_load_lds((const __attribute__((address_space(1))) void*)g,
                                     (__attribute__((address_space(3))) void*)l, 16, 0, 0);
}

// ---------------- kernels ----------------

__global__ void scatter_edges(float* __restrict__ A, const int* __restrict__ ei, int E, int n) {
    int e = blockIdx.x * 256 + threadIdx.x;
    if (e < E) {
        int r = ei[e];
        int c = ei[E + e];
        atomicAdd(&A[(size_t)r * n + c], 1.0f);
    }
}

__global__ void rowsum_dis(const float* __restrict__ A, int n, float* __restrict__ dis) {
    int row = blockIdx.x;
    __shared__ float sd[256];
    float s = 0.f;
    for (int c = threadIdx.x; c < n; c += 256) s += A[(size_t)row * n + c];
    sd[threadIdx.x] = s;
    __syncthreads();
    for (int st = 128; st > 0; st >>= 1) {
        if (threadIdx.x < st) sd[threadIdx.x] += sd[threadIdx.x + st];
        __syncthreads();
    }
    if (threadIdx.x == 0) dis[row] = 1.0f / sqrtf(sd[0] + 2.0f);
}

// C[i,o] = rs[i] * sum_k X[i,k] * W[o,k]    (X: n x K, W: m x K row-major)
__global__ void gemm_nt_scale(const float* __restrict__ X, const float* __restrict__ Wm,
                              float* __restrict__ C, int n, int K, int m,
                              const float* __restrict__ rs) {
    __shared__ float As[64][17];
    __shared__ float Bs[64][17];
    int tx = threadIdx.x & 15, ty = threadIdx.x >> 4;
    int rowBase = blockIdx.y * 64, colBase = blockIdx.x * 64;
    float acc[4][4] = {};
    for (int k0 = 0; k0 < K; k0 += 16) {
        for (int i = 0; i < 4; i++) {
            int l = threadIdx.x + i * 256;
            int r = l >> 4, c = l & 15;
            int gr = rowBase + r, gc = k0 + c;
            As[r][c] = (gr < n && gc < K) ? X[(size_t)gr * K + gc] : 0.f;
            int br = colBase + r;
            Bs[r][c] = (br < m && gc < K) ? Wm[(size_t)br * K + gc] : 0.f;
        }
        __syncthreads();
        for (int kk = 0; kk < 16; kk++) {
            float a[4], b[4];
            for (int i = 0; i < 4; i++) a[i] = As[ty * 4 + i][kk];
            for (int j = 0; j < 4; j++) b[j] = Bs[tx * 4 + j][kk];
            for (int i = 0; i < 4; i++)
                for (int j = 0; j < 4; j++) acc[i][j] += a[i] * b[j];
        }
        __syncthreads();
    }
    for (int i = 0; i < 4; i++) {
        int gr = rowBase + ty * 4 + i;
        if (gr >= n) continue;
        float rsv = rs ? rs[gr] : 1.0f;
        for (int j = 0; j < 4; j++) {
            int gc = colBase + tx * 4 + j;
            if (gc >= m) continue;
            C[(size_t)gr * m + gc] = rsv * acc[i][j];
        }
    }
}

// gcn epilogue GEMM: C[i,o] = dis[i]*(acc + 2*z[i,o]) + bias[o], optional relu
__global__ void gemm_nn(const float* __restrict__ A, const float* __restrict__ B,
                        float* __restrict__ C, int n, int K, int m,
                        const float* __restrict__ dis, const float* __restrict__ z,
                        const float* __restrict__ bias, int relu) {
    __shared__ float As[64][17];
    __shared__ float Bs[16][65];
    int tx = threadIdx.x & 15, ty = threadIdx.x >> 4;
    int rowBase = blockIdx.y * 64, colBase = blockIdx.x * 64;
    float acc[4][4] = {};
    for (int k0 = 0; k0 < K; k0 += 16) {
        for (int i = 0; i < 4; i++) {
            int l = threadIdx.x + i * 256;
            int r = l >> 4, c = l & 15;
            int gr = rowBase + r, gc = k0 + c;
            As[r][c] = (gr < n && gc < K) ? A[(size_t)gr * K + gc] : 0.f;
            int br = l >> 6, bc = l & 63;
            int gbr = k0 + br, gbc = colBase + bc;
            Bs[br][bc] = (gbr < K && gbc < m) ? B[(size_t)gbr * m + gbc] : 0.f;
        }
        __syncthreads();
        for (int kk = 0; kk < 16; kk++) {
            float a[4], b[4];
            for (int i = 0; i < 4; i++) a[i] = As[ty * 4 + i][kk];
            for (int j = 0; j < 4; j++) b[j] = Bs[kk][tx * 4 + j];
            for (int i = 0; i < 4; i++)
                for (int j = 0; j < 4; j++) acc[i][j] += a[i] * b[j];
        }
        __syncthreads();
    }
    for (int i = 0; i < 4; i++) {
        int gr = rowBase + ty * 4 + i;
        if (gr >= n) continue;
        for (int j = 0; j < 4; j++) {
            int gc = colBase + tx * 4 + j;
            if (gc >= m) continue;
            float v = acc[i][j];
            v = dis[gr] * (v + 2.0f * z[(size_t)gr * m + gc]) + bias[gc];
            if (relu) v = fmaxf(v, 0.f);
            C[(size_t)gr * m + gc] = v;
        }
    }
}

// Build padded bf16 A1 = A + I (hi), optional residual (lo). Pad with zeros.
__global__ void build_A1_bf16(const float* __restrict__ A, int n, int P,
                              unsigned short* __restrict__ H, unsigned short* __restrict__ L) {
    int idx = blockIdx.x * 256 + threadIdx.x;
    if (idx >= P * P) return;
    int r = idx / P, c = idx - r * P;
    float v = 0.f;
    if (r < n && c < n) v = (r == c) ? 1.0f : A[(size_t)r * n + c];
    unsigned u = __float_as_uint(v);
    unsigned hi = (u + 0x7FFFu + ((u >> 16) & 1u)) & 0xFFFF0000u;
    H[idx] = (unsigned short)(hi >> 16);
    if (L) {
        float rem = v - __uint_as_float(hi);
        unsigned ur = __float_as_uint(rem);
        unsigned lo = (ur + 0x7FFFu + ((ur >> 16) & 1u)) >> 16;
        L[idx] = (unsigned short)lo;
    }
}

// C = A * B^T (both row-major P x P bf16, P % 128 == 0), fp32 out.
// For symmetric B this equals A*B. m97-style: 128x128 tile, 4 waves,
// global_load_lds w16 (linear LDS) + XOR unit-swizzle on source & read.
__global__ __launch_bounds__(256) void mfma_sq(const unsigned short* __restrict__ A,
                                               const unsigned short* __restrict__ B,
                                               float* __restrict__ C, int P) {
    __shared__ __attribute__((aligned(16))) unsigned short lds[8192]; // A:[0,4096) B:[4096,8192)
    const int t = threadIdx.x;
    const int w = t >> 6, l = t & 63;
    const int lr = l & 15, lq = l >> 4;
    const int rowBase = blockIdx.y * 128, colBase = blockIdx.x * 128;
    const int wm = w >> 1, wn = w & 1;
    f32x4 acc[4][4] = {};

    // staging: physical unit u = pass*256 + t holds logical unit v = u ^ ((u>>2)&7)
    const int u0 = t, u1 = 256 + t;
    const int v0 = u0 ^ ((u0 >> 2) & 7), v1 = u1 ^ ((u1 >> 2) & 7);
    const int r0 = v0 >> 2, q0 = v0 & 3;
    const int r1 = v1 >> 2, q1 = v1 & 3;
    const unsigned short* gA0 = A + (size_t)(rowBase + r0) * P + q0 * 8;
    const unsigned short* gA1 = A + (size_t)(rowBase + r1) * P + q1 * 8;
    const unsigned short* gB0 = B + (size_t)(colBase + r0) * P + q0 * 8;
    const unsigned short* gB1 = B + (size_t)(colBase + r1) * P + q1 * 8;
    unsigned short* lA0 = &lds[(0 * 256 + w * 64) * 8];
    unsigned short* lA1 = &lds[(1 * 256 + w * 64) * 8];
    unsigned short* lB0 = &lds[4096 + (0 * 256 + w * 64) * 8];
    unsigned short* lB1 = &lds[4096 + (1 * 256 + w * 64) * 8];

    for (int k0 = 0; k0 < P; k0 += 32) {
        gload16(gA0 + k0, lA0);
        gload16(gA1 + k0, lA1);
        gload16(gB0 + k0, lB0);
        gload16(gB1 + k0, lB1);
        __syncthreads();  // drains vmcnt before barrier
        u32x4 af[4], bf[4];
        for (int i = 0; i < 4; i++) {
            int ra = wm * 64 + i * 16 + lr;
            int va = (ra * 4 + lq) ^ (ra & 7);
            af[i] = *(const u32x4*)&lds[va * 8];
            int rb = wn * 64 + i * 16 + lr;
            int vb = (rb * 4 + lq) ^ (rb & 7);
            bf[i] = *(const u32x4*)&lds[4096 + vb * 8];
        }
        for (int i = 0; i < 4; i++)
            for (int j = 0; j < 4; j++)
                mfma_bf16(acc[i][j], af[i], bf[j]);
        __syncthreads();
    }
    asm volatile("s_nop 7\n\ts_nop 7\n\ts_nop 7" ::: "memory"); // MFMA->VALU read hazard
    for (int i = 0; i < 4; i++)
        for (int j = 0; j < 4; j++)
            for (int r = 0; r < 4; r++) {
                int row = rowBase + wm * 64 + i * 16 + lq * 4 + r;
                int col = colBase + wn * 64 + j * 16 + lr;
                C[(size_t)row * P + col] = acc[i][j][r];
            }
}

__global__ void wnorm(const float* __restrict__ w, float* __restrict__ out) {
    __shared__ float sd[256];
    float v = w[threadIdx.x];
    sd[threadIdx.x] = v * v;
    __syncthreads();
    for (int st = 128; st > 0; st >>= 1) {
        if (threadIdx.x < st) sd[threadIdx.x] += sd[threadIdx.x + st];
        __syncthreads();
    }
    if (threadIdx.x == 0) out[0] = sqrtf(sd[0]);
}

__global__ void score_k(const float* __restrict__ x, const float* __restrict__ w,
                        const float* __restrict__ nrm, float* __restrict__ s) {
    int row = blockIdx.x;
    __shared__ float sd[256];
    sd[threadIdx.x] = x[(size_t)row * HF + threadIdx.x] * w[threadIdx.x];
    __syncthreads();
    for (int st = 128; st > 0; st >>= 1) {
        if (threadIdx.x < st) sd[threadIdx.x] += sd[threadIdx.x + st];
        __syncthreads();
    }
    if (threadIdx.x == 0) s[row] = tanhf(sd[0] / nrm[0]);
}

// single-block bitonic sort of up to 4096 keys; key = (~mapped_score << 32) | idx
__global__ __launch_bounds__(1024) void topk_sort(const float* __restrict__ s, int n,
                                                  int* __restrict__ perm, int k) {
    __shared__ unsigned long long sk[4096];
    for (int i = threadIdx.x; i < 4096; i += 1024) {
        unsigned long long key;
        if (i < n) {
            unsigned u = __float_as_uint(s[i]);
            u = (u & 0x80000000u) ? ~u : (u | 0x80000000u);
            unsigned inv = ~u;
            key = ((unsigned long long)inv << 32) | (unsigned)i;
        } else {
            key = 0xFFFFFFFFFFFFFFFFull;
        }
        sk[i] = key;
    }
    __syncthreads();
    for (int kk = 2; kk <= 4096; kk <<= 1) {
        for (int j = kk >> 1; j > 0; j >>= 1) {
            for (int i = threadIdx.x; i < 4096; i += 1024) {
                int ij = i ^ j;
                if (ij > i) {
                    bool up = ((i & kk) == 0);
                    unsigned long long a = sk[i], b = sk[ij];
                    if ((a > b) == up) { sk[i] = b; sk[ij] = a; }
                }
            }
            __syncthreads();
        }
    }
    for (int i = threadIdx.x; i < k; i += 1024) perm[i] = (int)(sk[i] & 0xFFFFFFFFu);
}

__global__ void gather_pool(const float* __restrict__ x, const int* __restrict__ perm,
                            const float* __restrict__ s, float* __restrict__ out) {
    int r = blockIdx.x, h = threadIdx.x;
    int p = perm[r];
    out[(size_t)r * HF + h] = x[(size_t)p * HF + h] * s[p];
}

// Aaug gathered: out[r,c] = (pr==pc) ? 0 : Cp[pr,pc] (+ Ct[pr,pc] + Ct[pc,pr] if split)
__global__ void gather_adj2(const float* __restrict__ Cp, const float* __restrict__ Ct,
                            const int* __restrict__ perm, float* __restrict__ out,
                            int P, int k) {
    int idx = blockIdx.x * 256 + threadIdx.x;
    if (idx >= k * k) return;
    int r = idx / k, c = idx - r * k;
    int pr = perm[r], pc = perm[c];
    float v = 0.f;
    if (pr != pc) {
        v = Cp[(size_t)pr * P + pc];
        if (Ct) v += Ct[(size_t)pr * P + pc] + Ct[(size_t)pc * P + pr];
    }
    out[idx] = v;
}

__global__ void scatter_add(float* __restrict__ out, const float* __restrict__ xs,
                            const int* __restrict__ perm) {
    int r = blockIdx.x, h = threadIdx.x;
    out[(size_t)perm[r] * HF + h] += xs[(size_t)r * HF + h];
}

// ---------------- host ----------------

extern "C" void kernel_launch(void* const* d_in, const int* in_sizes, int n_in,
                              void* d_out, int out_size, void* d_ws, size_t ws_size,
                              hipStream_t stream) {
    const int* edge_index = (const int*)d_in[0];
    const float* x_param = (const float*)d_in[1];
    const float* W_down = (const float*)d_in[2];
    const float* b_down = (const float*)d_in[3];
    const float* pool_w = (const float*)d_in[4];
    const float* W_up = (const float*)d_in[5];
    const float* b_up = (const float*)d_in[6];
    const float* W_out = (const float*)d_in[7];
    const float* b_out = (const float*)d_in[8];
    float* out = (float*)d_out;

    const int E = in_sizes[0] / 2;  // 96000
    const int KS[3] = {2000, 1000, 500};

    float* w = (float*)d_ws;
    size_t off = 0;
    auto alloc = [&](size_t cnt) { float* p = w + off; off += cnt; return p; };
    float* As0 = alloc(9000000);
    float* As1 = alloc(4000000);
    float* As2 = alloc(1000000);
    float* A3  = alloc(250000);
    unsigned short* Ah = (unsigned short*)alloc(3072 * 3072 / 2);  // bf16 hi, padded
    unsigned short* Al = (unsigned short*)alloc(1024 * 1024 / 2);  // bf16 lo (level 2)
    float* Cp = alloc(3072 * 3072);
    float* Ct = alloc(1024 * 1024);
    float* xs0 = alloc(768000);
    float* xs1 = alloc(512000);
    float* xs2 = alloc(256000);
    float* xp  = alloc(768000);
    float* xq  = alloc(768000);
    float* zt  = alloc(768000);
    float* sc  = alloc(3008);
    float* dis = alloc(3008);
    float* nrm = alloc(8);
    int* perm0 = (int*)alloc(2000);
    int* perm1 = (int*)alloc(1024);
    int* perm2 = (int*)alloc(512);

    auto gcn = [&](const float* A, const float* x, const float* Wm, const float* b,
                   int n, int fout, float* outp, int relu) {
        rowsum_dis<<<n, 256, 0, stream>>>(A, n, dis);
        dim3 gnt((fout + 63) / 64, (n + 63) / 64);
        gemm_nt_scale<<<gnt, 256, 0, stream>>>(x, Wm, zt, n, HF, fout, dis);
        dim3 gnn((fout + 63) / 64, (n + 63) / 64);
        gemm_nn<<<gnn, 256, 0, stream>>>(A, zt, outp, n, n, fout, dis, zt, b, relu);
    };

    // build A0
    hipMemsetAsync(As0, 0, (size_t)NN * NN * sizeof(float), stream);
    scatter_edges<<<(E + 255) / 256, 256, 0, stream>>>(As0, edge_index, E, NN);

    // x0 = relu(gcn(A0, x_param, Wd0, bd0))
    gcn(As0, x_param, W_down, b_down, NN, HF, xs0, 1);

    const float* Alev[3] = {As0, As1, As2};
    float* Anext[3] = {As1, As2, A3};
    int* perms[3] = {perm0, perm1, perm2};
    const float* xlev[3] = {xs0, xs1, xs2};
    float* xnext[3] = {xs1, xs2, xq};
    int ns[4] = {NN, 2000, 1000, 500};
    int Ps[3] = {3072, 2048, 1024};

    for (int i = 0; i < 3; i++) {
        int n = ns[i], k = KS[i], P = Ps[i];
        bool split = (i == 2);  // level-2 entries can exceed bf16-exact 255
        build_A1_bf16<<<(P * P + 255) / 256, 256, 0, stream>>>(Alev[i], n, P, Ah,
                                                               split ? Al : nullptr);
        dim3 g(P / 128, P / 128);
        mfma_sq<<<g, 256, 0, stream>>>(Ah, Ah, Cp, P);           // H*H
        if (split)
            mfma_sq<<<g, 256, 0, stream>>>(Ah, Al, Ct, P);       // H*L (sym -> +transpose)
        // scores
        wnorm<<<1, 256, 0, stream>>>(pool_w + (size_t)i * HF, nrm);
        score_k<<<n, 256, 0, stream>>>(xlev[i], pool_w + (size_t)i * HF, nrm, sc);
        topk_sort<<<1, 1024, 0, stream>>>(sc, n, perms[i], k);
        // pool
        gather_pool<<<k, 256, 0, stream>>>(xlev[i], perms[i], sc, xp);
        gather_adj2<<<(k * k + 255) / 256, 256, 0, stream>>>(Cp, split ? Ct : nullptr,
                                                             perms[i], Anext[i], P, k);
        // down gcn
        gcn(Anext[i], xp, W_down + (size_t)(i + 1) * HF * HF, b_down + (size_t)(i + 1) * HF,
            k, HF, xnext[i], 1);
    }

    // up path: x currently in xq (500 x 256)
    {
        hipMemcpyAsync(xp, xs2, (size_t)1000 * HF * sizeof(float),
                       hipMemcpyDeviceToDevice, stream);
        scatter_add<<<500, 256, 0, stream>>>(xp, xq, perm2);
        gcn(As2, xp, W_up, b_up, 1000, HF, xq, 1);
    }
    {
        hipMemcpyAsync(xp, xs1, (size_t)2000 * HF * sizeof(float),
                       hipMemcpyDeviceToDevice, stream);
        scatter_add<<<1000, 256, 0, stream>>>(xp, xq, perm1);
        gcn(As1, xp, W_up + (size_t)HF * HF, b_up + HF, 2000, HF, xq, 1);
    }
    {
        hipMemcpyAsync(xp, xs0, (size_t)NN * HF * sizeof(float),
                       hipMemcpyDeviceToDevice, stream);
        scatter_add<<<2000, 256, 0, stream>>>(xp, xq, perm0);
        gcn(As0, xp, W_out, b_out, NN, 40, out, 0);
    }
}

// Round 3
// 1250.367 us; speedup vs baseline: 3.9755x; 2.2901x over previous
//
#include <hip/hip_runtime.h>
#include <math.h>

#define NN 3000
#define HF 256

typedef __attribute__((ext_vector_type(4))) float f32x4;
typedef __attribute__((ext_vector_type(4))) unsigned int u32x4;

__device__ inline void mfma_bf16(f32x4& d, u32x4 a, u32x4 b) {
    asm("v_mfma_f32_16x16x32_bf16 %0, %1, %2, %0" : "+v"(d) : "v"(a), "v"(b));
}

__device__ inline void gload16(const void* g, void* l) {
    __builtin_amdgcn_global_load_lds((const __attribute__((address_space(1))) void*)g,
                                     (__attribute__((address_space(3))) void*)l, 16, 0, 0);
}

// ---------------- kernels ----------------

__global__ void scatter_edges(float* __restrict__ A, const int* __restrict__ ei, int E, int n) {
    int e = blockIdx.x * 256 + threadIdx.x;
    if (e < E) {
        int r = ei[e];
        int c = ei[E + e];
        atomicAdd(&A[(size_t)r * n + c], 1.0f);
    }
}

__global__ void rowsum_dis(const float* __restrict__ A, int n, float* __restrict__ dis) {
    int row = blockIdx.x;
    __shared__ float sd[256];
    float s = 0.f;
    for (int c = threadIdx.x; c < n; c += 256) s += A[(size_t)row * n + c];
    sd[threadIdx.x] = s;
    __syncthreads();
    for (int st = 128; st > 0; st >>= 1) {
        if (threadIdx.x < st) sd[threadIdx.x] += sd[threadIdx.x + st];
        __syncthreads();
    }
    if (threadIdx.x == 0) dis[row] = 1.0f / sqrtf(sd[0] + 2.0f);
}

// C[i,o] = rs[i] * sum_k X[i,k] * W[o,k]    (X: n x K, W: m x K row-major)
__global__ void gemm_nt_scale(const float* __restrict__ X, const float* __restrict__ Wm,
                              float* __restrict__ C, int n, int K, int m,
                              const float* __restrict__ rs) {
    __shared__ float As[64][17];
    __shared__ float Bs[64][17];
    int tx = threadIdx.x & 15, ty = threadIdx.x >> 4;
    int rowBase = blockIdx.y * 64, colBase = blockIdx.x * 64;
    float acc[4][4] = {};
    for (int k0 = 0; k0 < K; k0 += 16) {
        for (int i = 0; i < 4; i++) {
            int l = threadIdx.x + i * 256;
            int r = l >> 4, c = l & 15;
            int gr = rowBase + r, gc = k0 + c;
            As[r][c] = (gr < n && gc < K) ? X[(size_t)gr * K + gc] : 0.f;
            int br = colBase + r;
            Bs[r][c] = (br < m && gc < K) ? Wm[(size_t)br * K + gc] : 0.f;
        }
        __syncthreads();
        for (int kk = 0; kk < 16; kk++) {
            float a[4], b[4];
            for (int i = 0; i < 4; i++) a[i] = As[ty * 4 + i][kk];
            for (int j = 0; j < 4; j++) b[j] = Bs[tx * 4 + j][kk];
            for (int i = 0; i < 4; i++)
                for (int j = 0; j < 4; j++) acc[i][j] += a[i] * b[j];
        }
        __syncthreads();
    }
    for (int i = 0; i < 4; i++) {
        int gr = rowBase + ty * 4 + i;
        if (gr >= n) continue;
        float rsv = rs ? rs[gr] : 1.0f;
        for (int j = 0; j < 4; j++) {
            int gc = colBase + tx * 4 + j;
            if (gc >= m) continue;
            C[(size_t)gr * m + gc] = rsv * acc[i][j];
        }
    }
}

// split-K partial GEMM: P[z][i,o] = sum_{k in chunk z} A[i,k]*B[k,o]
__global__ void gemm_splitk(const float* __restrict__ A, const float* __restrict__ B,
                            float* __restrict__ P, int n, int K, int m, int kc) {
    __shared__ float As[64][17];
    __shared__ float Bs[16][65];
    int tx = threadIdx.x & 15, ty = threadIdx.x >> 4;
    int rowBase = blockIdx.y * 64, colBase = blockIdx.x * 64;
    int kBeg = blockIdx.z * kc;
    int kEnd = min(K, kBeg + kc);
    float acc[4][4] = {};
    for (int k0 = kBeg; k0 < kEnd; k0 += 16) {
        for (int i = 0; i < 4; i++) {
            int l = threadIdx.x + i * 256;
            int r = l >> 4, c = l & 15;
            int gr = rowBase + r, gc = k0 + c;
            As[r][c] = (gr < n && gc < kEnd) ? A[(size_t)gr * K + gc] : 0.f;
            int br = l >> 6, bc = l & 63;
            int gbr = k0 + br, gbc = colBase + bc;
            Bs[br][bc] = (gbr < kEnd && gbc < m) ? B[(size_t)gbr * m + gbc] : 0.f;
        }
        __syncthreads();
        for (int kk = 0; kk < 16; kk++) {
            float a[4], b[4];
            for (int i = 0; i < 4; i++) a[i] = As[ty * 4 + i][kk];
            for (int j = 0; j < 4; j++) b[j] = Bs[kk][tx * 4 + j];
            for (int i = 0; i < 4; i++)
                for (int j = 0; j < 4; j++) acc[i][j] += a[i] * b[j];
        }
        __syncthreads();
    }
    float* Pz = P + (size_t)blockIdx.z * n * m;
    for (int i = 0; i < 4; i++) {
        int gr = rowBase + ty * 4 + i;
        if (gr >= n) continue;
        for (int j = 0; j < 4; j++) {
            int gc = colBase + tx * 4 + j;
            if (gc >= m) continue;
            Pz[(size_t)gr * m + gc] = acc[i][j];
        }
    }
}

// out[i,o] = dis[i]*(sum_z P[z][i,o] + 2*z[i,o]) + bias[o], optional relu
__global__ void reduce_gcn(const float* __restrict__ P, int nch, int n, int m,
                           const float* __restrict__ dis, const float* __restrict__ z,
                           const float* __restrict__ bias, int relu,
                           float* __restrict__ C) {
    int idx = blockIdx.x * 256 + threadIdx.x;
    if (idx >= n * m) return;
    int i = idx / m, o = idx - i * m;
    float s = 0.f;
    for (int c = 0; c < nch; c++) s += P[(size_t)c * n * m + idx];
    float v = dis[i] * (s + 2.0f * z[idx]) + bias[o];
    if (relu) v = fmaxf(v, 0.f);
    C[idx] = v;
}

// Build padded bf16 A1 = A + I (hi), optional residual (lo). Pad with zeros.
__global__ void build_A1_bf16(const float* __restrict__ A, int n, int P,
                              unsigned short* __restrict__ H, unsigned short* __restrict__ L) {
    int idx = blockIdx.x * 256 + threadIdx.x;
    if (idx >= P * P) return;
    int r = idx / P, c = idx - r * P;
    float v = 0.f;
    if (r < n && c < n) v = (r == c) ? 1.0f : A[(size_t)r * n + c];
    unsigned u = __float_as_uint(v);
    unsigned hi = (u + 0x7FFFu + ((u >> 16) & 1u)) & 0xFFFF0000u;
    H[idx] = (unsigned short)(hi >> 16);
    if (L) {
        float rem = v - __uint_as_float(hi);
        unsigned ur = __float_as_uint(rem);
        unsigned lo = (ur + 0x7FFFu + ((ur >> 16) & 1u)) >> 16;
        L[idx] = (unsigned short)lo;
    }
}

// C = A * B^T (both row-major P x P bf16, P % 128 == 0), fp32 out.
__global__ __launch_bounds__(256) void mfma_sq(const unsigned short* __restrict__ A,
                                               const unsigned short* __restrict__ B,
                                               float* __restrict__ C, int P) {
    __shared__ __attribute__((aligned(16))) unsigned short lds[8192];
    const int t = threadIdx.x;
    const int w = t >> 6, l = t & 63;
    const int lr = l & 15, lq = l >> 4;
    const int rowBase = blockIdx.y * 128, colBase = blockIdx.x * 128;
    const int wm = w >> 1, wn = w & 1;
    f32x4 acc[4][4] = {};

    const int u0 = t, u1 = 256 + t;
    const int v0 = u0 ^ ((u0 >> 2) & 7), v1 = u1 ^ ((u1 >> 2) & 7);
    const int r0 = v0 >> 2, q0 = v0 & 3;
    const int r1 = v1 >> 2, q1 = v1 & 3;
    const unsigned short* gA0 = A + (size_t)(rowBase + r0) * P + q0 * 8;
    const unsigned short* gA1 = A + (size_t)(rowBase + r1) * P + q1 * 8;
    const unsigned short* gB0 = B + (size_t)(colBase + r0) * P + q0 * 8;
    const unsigned short* gB1 = B + (size_t)(colBase + r1) * P + q1 * 8;
    unsigned short* lA0 = &lds[(0 * 256 + w * 64) * 8];
    unsigned short* lA1 = &lds[(1 * 256 + w * 64) * 8];
    unsigned short* lB0 = &lds[4096 + (0 * 256 + w * 64) * 8];
    unsigned short* lB1 = &lds[4096 + (1 * 256 + w * 64) * 8];

    for (int k0 = 0; k0 < P; k0 += 32) {
        gload16(gA0 + k0, lA0);
        gload16(gA1 + k0, lA1);
        gload16(gB0 + k0, lB0);
        gload16(gB1 + k0, lB1);
        __syncthreads();
        u32x4 af[4], bf[4];
        for (int i = 0; i < 4; i++) {
            int ra = wm * 64 + i * 16 + lr;
            int va = (ra * 4 + lq) ^ (ra & 7);
            af[i] = *(const u32x4*)&lds[va * 8];
            int rb = wn * 64 + i * 16 + lr;
            int vb = (rb * 4 + lq) ^ (rb & 7);
            bf[i] = *(const u32x4*)&lds[4096 + vb * 8];
        }
        for (int i = 0; i < 4; i++)
            for (int j = 0; j < 4; j++)
                mfma_bf16(acc[i][j], af[i], bf[j]);
        __syncthreads();
    }
    asm volatile("s_nop 7\n\ts_nop 7\n\ts_nop 7" ::: "memory");
    for (int i = 0; i < 4; i++)
        for (int j = 0; j < 4; j++)
            for (int r = 0; r < 4; r++) {
                int row = rowBase + wm * 64 + i * 16 + lq * 4 + r;
                int col = colBase + wn * 64 + j * 16 + lr;
                C[(size_t)row * P + col] = acc[i][j][r];
            }
}

__global__ void wnorm(const float* __restrict__ w, float* __restrict__ out) {
    __shared__ float sd[256];
    float v = w[threadIdx.x];
    sd[threadIdx.x] = v * v;
    __syncthreads();
    for (int st = 128; st > 0; st >>= 1) {
        if (threadIdx.x < st) sd[threadIdx.x] += sd[threadIdx.x + st];
        __syncthreads();
    }
    if (threadIdx.x == 0) out[0] = sqrtf(sd[0]);
}

__global__ void score_k(const float* __restrict__ x, const float* __restrict__ w,
                        const float* __restrict__ nrm, float* __restrict__ s) {
    int row = blockIdx.x;
    __shared__ float sd[256];
    sd[threadIdx.x] = x[(size_t)row * HF + threadIdx.x] * w[threadIdx.x];
    __syncthreads();
    for (int st = 128; st > 0; st >>= 1) {
        if (threadIdx.x < st) sd[threadIdx.x] += sd[threadIdx.x + st];
        __syncthreads();
    }
    if (threadIdx.x == 0) s[row] = tanhf(sd[0] / nrm[0]);
}

// single-block bitonic sort of up to 4096 keys; key = (~mapped_score << 32) | idx
__global__ __launch_bounds__(1024) void topk_sort(const float* __restrict__ s, int n,
                                                  int* __restrict__ perm, int k) {
    __shared__ unsigned long long sk[4096];
    for (int i = threadIdx.x; i < 4096; i += 1024) {
        unsigned long long key;
        if (i < n) {
            unsigned u = __float_as_uint(s[i]);
            u = (u & 0x80000000u) ? ~u : (u | 0x80000000u);
            unsigned inv = ~u;
            key = ((unsigned long long)inv << 32) | (unsigned)i;
        } else {
            key = 0xFFFFFFFFFFFFFFFFull;
        }
        sk[i] = key;
    }
    __syncthreads();
    for (int kk = 2; kk <= 4096; kk <<= 1) {
        for (int j = kk >> 1; j > 0; j >>= 1) {
            for (int i = threadIdx.x; i < 4096; i += 1024) {
                int ij = i ^ j;
                if (ij > i) {
                    bool up = ((i & kk) == 0);
                    unsigned long long a = sk[i], b = sk[ij];
                    if ((a > b) == up) { sk[i] = b; sk[ij] = a; }
                }
            }
            __syncthreads();
        }
    }
    for (int i = threadIdx.x; i < k; i += 1024) perm[i] = (int)(sk[i] & 0xFFFFFFFFu);
}

__global__ void gather_pool(const float* __restrict__ x, const int* __restrict__ perm,
                            const float* __restrict__ s, float* __restrict__ out) {
    int r = blockIdx.x, h = threadIdx.x;
    int p = perm[r];
    out[(size_t)r * HF + h] = x[(size_t)p * HF + h] * s[p];
}

__global__ void gather_adj2(const float* __restrict__ Cp, const float* __restrict__ Ct,
                            const int* __restrict__ perm, float* __restrict__ out,
                            int P, int k) {
    int idx = blockIdx.x * 256 + threadIdx.x;
    if (idx >= k * k) return;
    int r = idx / k, c = idx - r * k;
    int pr = perm[r], pc = perm[c];
    float v = 0.f;
    if (pr != pc) {
        v = Cp[(size_t)pr * P + pc];
        if (Ct) v += Ct[(size_t)pr * P + pc] + Ct[(size_t)pc * P + pr];
    }
    out[idx] = v;
}

__global__ void scatter_add(float* __restrict__ out, const float* __restrict__ xs,
                            const int* __restrict__ perm) {
    int r = blockIdx.x, h = threadIdx.x;
    out[(size_t)perm[r] * HF + h] += xs[(size_t)r * HF + h];
}

// ---------------- host ----------------

extern "C" void kernel_launch(void* const* d_in, const int* in_sizes, int n_in,
                              void* d_out, int out_size, void* d_ws, size_t ws_size,
                              hipStream_t stream) {
    const int* edge_index = (const int*)d_in[0];
    const float* x_param = (const float*)d_in[1];
    const float* W_down = (const float*)d_in[2];
    const float* b_down = (const float*)d_in[3];
    const float* pool_w = (const float*)d_in[4];
    const float* W_up = (const float*)d_in[5];
    const float* b_up = (const float*)d_in[6];
    const float* W_out = (const float*)d_in[7];
    const float* b_out = (const float*)d_in[8];
    float* out = (float*)d_out;

    const int E = in_sizes[0] / 2;  // 96000
    const int KS[3] = {2000, 1000, 500};

    float* w = (float*)d_ws;
    size_t off = 0;
    auto alloc = [&](size_t cnt) { float* p = w + off; off += cnt; return p; };
    float* As0 = alloc(9000000);
    float* As1 = alloc(4000000);
    float* As2 = alloc(1000000);
    float* A3  = alloc(250000);
    unsigned short* Ah = (unsigned short*)alloc(3072 * 3072 / 2);
    unsigned short* Al = (unsigned short*)alloc(1024 * 1024 / 2);
    float* Cp = alloc(3072 * 3072);     // mfma out; reused as split-K partial space
    float* Ct = alloc(1024 * 1024);
    float* xs0 = alloc(768000);
    float* xs1 = alloc(512000);
    float* xs2 = alloc(256000);
    float* xp  = alloc(768000);
    float* xq  = alloc(768000);
    float* zt  = alloc(768000);
    float* sc  = alloc(3008);
    float* dis = alloc(3008);
    float* nrm = alloc(8);
    int* perm0 = (int*)alloc(2000);
    int* perm1 = (int*)alloc(1024);
    int* perm2 = (int*)alloc(512);

    auto gcn = [&](const float* A, const float* x, const float* Wm, const float* b,
                   int n, int fout, float* outp, int relu) {
        rowsum_dis<<<n, 256, 0, stream>>>(A, n, dis);
        dim3 gnt((fout + 63) / 64, (n + 63) / 64);
        gemm_nt_scale<<<gnt, 256, 0, stream>>>(x, Wm, zt, n, HF, fout, dis);
        // split-K aggregation: A (n x n) @ zt (n x fout)
        int bb = ((fout + 63) / 64) * ((n + 63) / 64);
        int nch = 1;
        while (bb * nch < 512 && nch < 16) nch <<= 1;
        int kc = ((n + nch - 1) / nch + 15) & ~15;
        nch = (n + kc - 1) / kc;
        dim3 g((fout + 63) / 64, (n + 63) / 64, nch);
        gemm_splitk<<<g, 256, 0, stream>>>(A, zt, Cp, n, n, fout, kc);
        reduce_gcn<<<(n * fout + 255) / 256, 256, 0, stream>>>(Cp, nch, n, fout, dis, zt,
                                                               b, relu, outp);
    };

    // build A0
    hipMemsetAsync(As0, 0, (size_t)NN * NN * sizeof(float), stream);
    scatter_edges<<<(E + 255) / 256, 256, 0, stream>>>(As0, edge_index, E, NN);

    gcn(As0, x_param, W_down, b_down, NN, HF, xs0, 1);

    const float* Alev[3] = {As0, As1, As2};
    float* Anext[3] = {As1, As2, A3};
    int* perms[3] = {perm0, perm1, perm2};
    const float* xlev[3] = {xs0, xs1, xs2};
    float* xnext[3] = {xs1, xs2, xq};
    int ns[4] = {NN, 2000, 1000, 500};
    int Ps[3] = {3072, 2048, 1024};

    for (int i = 0; i < 3; i++) {
        int n = ns[i], k = KS[i], P = Ps[i];
        bool split = (i == 2);
        build_A1_bf16<<<(P * P + 255) / 256, 256, 0, stream>>>(Alev[i], n, P, Ah,
                                                               split ? Al : nullptr);
        dim3 g(P / 128, P / 128);
        mfma_sq<<<g, 256, 0, stream>>>(Ah, Ah, Cp, P);
        if (split)
            mfma_sq<<<g, 256, 0, stream>>>(Ah, Al, Ct, P);
        wnorm<<<1, 256, 0, stream>>>(pool_w + (size_t)i * HF, nrm);
        score_k<<<n, 256, 0, stream>>>(xlev[i], pool_w + (size_t)i * HF, nrm, sc);
        topk_sort<<<1, 1024, 0, stream>>>(sc, n, perms[i], k);
        gather_pool<<<k, 256, 0, stream>>>(xlev[i], perms[i], sc, xp);
        gather_adj2<<<(k * k + 255) / 256, 256, 0, stream>>>(Cp, split ? Ct : nullptr,
                                                             perms[i], Anext[i], P, k);
        gcn(Anext[i], xp, W_down + (size_t)(i + 1) * HF * HF, b_down + (size_t)(i + 1) * HF,
            k, HF, xnext[i], 1);
    }

    // up path: x currently in xq (500 x 256)
    {
        hipMemcpyAsync(xp, xs2, (size_t)1000 * HF * sizeof(float),
                       hipMemcpyDeviceToDevice, stream);
        scatter_add<<<500, 256, 0, stream>>>(xp, xq, perm2);
        gcn(As2, xp, W_up, b_up, 1000, HF, xq, 1);
    }
    {
        hipMemcpyAsync(xp, xs1, (size_t)2000 * HF * sizeof(float),
                       hipMemcpyDeviceToDevice, stream);
        scatter_add<<<1000, 256, 0, stream>>>(xp, xq, perm1);
        gcn(As1, xp, W_up + (size_t)HF * HF, b_up + HF, 2000, HF, xq, 1);
    }
    {
        hipMemcpyAsync(xp, xs0, (size_t)NN * HF * sizeof(float),
                       hipMemcpyDeviceToDevice, stream);
        scatter_add<<<2000, 256, 0, stream>>>(xp, xq, perm0);
        gcn(As0, xp, W_out, b_out, NN, 40, out, 0);
    }
}